// Round 4
// baseline (1181.603 us; speedup 1.0000x reference)
//
#include <hip/hip_runtime.h>

#define NPTS 4096
#define NCH  64
#define NB   8
#define KNN  16

typedef double d4 __attribute__((ext_vector_type(4)));

// ---------------- K1: xx[b,n] = sum_c x^2 in fp64 (effectively exact) ---------
__global__ __launch_bounds__(256) void k_xx(const float* __restrict__ x,
                                            double* __restrict__ xx) {
    int g = blockIdx.x * 256 + threadIdx.x;        // [0, 8*4096)
    int b = g >> 12, n = g & 4095;
    const float* xp = x + (size_t)b * NCH * NPTS + n;
    double acc = 0.0;
    #pragma unroll
    for (int c = 0; c < NCH; ++c) {
        double v = (double)xp[(size_t)c * NPTS];
        acc = fma(v, v, acc);
    }
    xx[g] = acc;
}

// ---------------- K2: KNN top-16 per query, fp64 distances --------------------
// GEMM via f64 MFMA with per-wave runtime layout verification (asymmetric
// probe, G9-compliant); on mismatch, fall back to VALU fp64 dots producing
// the exact same sD entries. Scan: branch-free sorted-insert of f64-packed
// (2*dot - xx_m, idx); per-query-constant xx_q dropped (set-invariant).
__global__ __launch_bounds__(256) void k_knn(const float* __restrict__ x,
                                             const double* __restrict__ xx,
                                             int* __restrict__ idx_out) {
    __shared__ __align__(16) float  sQ[64 * 72];   // [c][q] pad 72
    __shared__ __align__(16) float  sM[64 * 72];   // [c][m] pad 72
    __shared__ __align__(16) double sD[64 * 68];   // [q][m] pad 68
    __shared__ __align__(16) double sXm[64];

    const int tid  = threadIdx.x;
    const int lane = tid & 63;
    const int w    = tid >> 6;                     // wave id: query rows 16w..16w+15
    const int b    = blockIdx.y;
    const int q0   = blockIdx.x * 64;
    const float*  xb  = x  + (size_t)b * NCH * NPTS;
    const double* xxb = xx + (size_t)b * NPTS;

    for (int i = tid; i < 4096; i += 256) {
        int c = i >> 6, q = i & 63;
        sQ[c * 72 + q] = xb[(size_t)c * NPTS + q0 + q];
    }
    __syncthreads();

    // Assumed fragment layout (to be verified): A[i][k] in lane 16k+i;
    // B[k][j] in lane 16k+j; D[i][j]: col j = lane&15, row i = 4*(lane>>4)+reg.
    const int g = lane >> 4, j = lane & 15;
    double Aq[16];
    #pragma unroll
    for (int kk = 0; kk < 16; ++kk)
        Aq[kk] = (double)sQ[(4 * kk + g) * 72 + 16 * w + j];

    // ---- one-shot asymmetric layout probe (B = Q cols shifted by 1) ----
    bool mfma_ok;
    {
        const int jn = (j + 1) & 15;
        d4 p = {0.0, 0.0, 0.0, 0.0};
        #pragma unroll
        for (int kk = 0; kk < 16; ++kk) {
            double bv = (double)sQ[(4 * kk + g) * 72 + 16 * w + jn];
            p = __builtin_amdgcn_mfma_f64_16x16x4f64(Aq[kk], bv, p, 0, 0, 0);
        }
        double r0 = 0.0, r3 = 0.0;
        #pragma unroll 8
        for (int c = 0; c < 64; ++c) {
            double bq = (double)sQ[c * 72 + 16 * w + jn];
            r0 = fma((double)sQ[c * 72 + 16 * w + 4 * g    ], bq, r0);
            r3 = fma((double)sQ[c * 72 + 16 * w + 4 * g + 3], bq, r3);
        }
        bool bad = (fabs(p[0] - r0) > 1e-6 * (1.0 + fabs(r0))) ||
                   (fabs(p[3] - r3) > 1e-6 * (1.0 + fabs(r3)));
        mfma_ok = !__any(bad ? 1 : 0);   // wave-uniform
    }

    double s[16];
    #pragma unroll
    for (int i = 0; i < 16; ++i) s[i] = 0.0;

    const int sc = tid & 3, qq = tid >> 2;         // scan: 4 scanners per query

    for (int t = 0; t < 64; ++t) {
        const int m0 = t * 64;
        for (int i = tid; i < 4096; i += 256) {
            int c = i >> 6, m = i & 63;
            sM[c * 72 + m] = xb[(size_t)c * NPTS + m0 + m];
        }
        __syncthreads();   // SYNC_A: sM ready AND all prior-tile scans finished

        if (tid < 64) sXm[tid] = xxb[m0 + tid];    // ordered: after SYNC_A, before SYNC_B

        if (mfma_ok) {
            // D[16q x 64m] per wave: 4 m-tiles, K=64 as 16 steps of K=4.
            d4 acc0 = {0.0, 0.0, 0.0, 0.0};
            d4 acc1 = acc0, acc2 = acc0, acc3 = acc0;
            const float* bp = sM + g * 72 + j;
            #pragma unroll
            for (int kk = 0; kk < 16; ++kk) {
                const float* bk = bp + kk * 4 * 72;
                double b0 = (double)bk[0];
                double b1 = (double)bk[16];
                double b2 = (double)bk[32];
                double b3 = (double)bk[48];
                acc0 = __builtin_amdgcn_mfma_f64_16x16x4f64(Aq[kk], b0, acc0, 0, 0, 0);
                acc1 = __builtin_amdgcn_mfma_f64_16x16x4f64(Aq[kk], b1, acc1, 0, 0, 0);
                acc2 = __builtin_amdgcn_mfma_f64_16x16x4f64(Aq[kk], b2, acc2, 0, 0, 0);
                acc3 = __builtin_amdgcn_mfma_f64_16x16x4f64(Aq[kk], b3, acc3, 0, 0, 0);
            }
            const int rbase = 16 * w + 4 * g;
            #pragma unroll
            for (int r = 0; r < 4; ++r) {
                double* dst = sD + (size_t)(rbase + r) * 68 + j;
                dst[0]  = acc0[r];
                dst[16] = acc1[r];
                dst[32] = acc2[r];
                dst[48] = acc3[r];
            }
        } else {
            // fallback: lane computes the same 16 entries by direct fp64 dots
            #pragma unroll
            for (int r = 0; r < 4; ++r) {
                const int qrow = 16 * w + 4 * g + r;
                double d0 = 0.0, d1 = 0.0, d2 = 0.0, d3 = 0.0;
                #pragma unroll 8
                for (int c = 0; c < 64; ++c) {
                    double a = (double)sQ[c * 72 + qrow];
                    d0 = fma(a, (double)sM[c * 72 + j     ], d0);
                    d1 = fma(a, (double)sM[c * 72 + j + 16], d1);
                    d2 = fma(a, (double)sM[c * 72 + j + 32], d2);
                    d3 = fma(a, (double)sM[c * 72 + j + 48], d3);
                }
                double* dst = sD + (size_t)qrow * 68 + j;
                dst[0] = d0; dst[16] = d1; dst[32] = d2; dst[48] = d3;
            }
        }
        __syncthreads();   // SYNC_B: sD + sXm ready for scan

        const double* row = sD + (size_t)qq * 68;
        #pragma unroll
        for (int jj = 0; jj < 16; ++jj) {
            int m = sc + 4 * jj;
            double dot = row[m];
            double dv  = fma(2.0, dot, -sXm[m]);       // ordering == true dist
            double pv  = dv + 4096.0;                  // positive, exp ~2^11-12
            unsigned long long bits =
                (((unsigned long long)__double_as_longlong(pv)) & 0xFFFFFFFFFFFFF000ULL)
                | (unsigned long long)(4095 - (m0 + m));   // ties -> lower idx wins
            double v = __longlong_as_double((long long)bits);
            #pragma unroll
            for (int i = 0; i < 15; ++i) s[i] = fmin(s[i + 1], fmax(v, s[i]));
            s[15] = fmax(v, s[15]);
        }
    }

    // merge the 4 scanners' lists per query (reuse sD: 4096 doubles <= 4352)
    double* mbuf = sD;
    __syncthreads();
    #pragma unroll
    for (int i = 0; i < 16; ++i) mbuf[(size_t)qq * 64 + sc * 16 + i] = s[i];
    __syncthreads();
    if (tid < 64) {
        double tb[16];
        #pragma unroll
        for (int i = 0; i < 16; ++i) tb[i] = 0.0;
        const double* src = mbuf + (size_t)tid * 64;
        #pragma unroll 4
        for (int e = 0; e < 64; ++e) {
            double v = src[e];
            #pragma unroll
            for (int i = 0; i < 15; ++i) tb[i] = fmin(tb[i + 1], fmax(v, tb[i]));
            tb[15] = fmax(v, tb[15]);
        }
        int* op = idx_out + ((size_t)b * NPTS + q0 + tid) * KNN;
        #pragma unroll
        for (int i = 0; i < 16; ++i) {
            int code = (int)((unsigned long long)__double_as_longlong(tb[i]) & 0xFFFULL);
            op[i] = 4095 - code;
        }
    }
}

// ---------------- K3: P = W1 * x ; Q = (W2 - W1) * x  (both [b][n][o]) --------
__global__ __launch_bounds__(256) void k_pq(const float* __restrict__ x,
                                            const float* __restrict__ W,
                                            float* __restrict__ P,
                                            float* __restrict__ Q) {
    __shared__ __align__(16) float sX[4096];    // [c][m] 64x64
    __shared__ __align__(16) float sWt[8192];   // [c][oc] 64x128 (oc<64:W1, >=64:W2-W1)
    const int tid = threadIdx.x;
    const int g0  = blockIdx.x * 64;            // global row = b*4096 + n
    const int b   = g0 >> 12;
    const int n0  = g0 & 4095;
    const float* xb = x + (size_t)b * NCH * NPTS;

    for (int i = tid; i < 8192; i += 256) {
        int c = i >> 7, oc = i & 127;
        float wv;
        if (oc < 64) wv = W[oc * 128 + c];
        else { int o = oc - 64; wv = W[o * 128 + 64 + c] - W[o * 128 + c]; }
        sWt[c * 128 + oc] = wv;
    }
    for (int i = tid; i < 4096; i += 256) {
        int c = i >> 6, m = i & 63;
        sX[i] = xb[(size_t)c * NPTS + n0 + m];
    }
    __syncthreads();

    const int ty = tid >> 4, tx = tid & 15;
    float aP[4][4], aQ[4][4];
    #pragma unroll
    for (int i = 0; i < 4; ++i)
        #pragma unroll
        for (int j = 0; j < 4; ++j) { aP[i][j] = 0.f; aQ[i][j] = 0.f; }

    const float4* a4 = (const float4*)sX + ty;
    const float4* p4 = (const float4*)sWt + tx;
    const float4* q4 = (const float4*)sWt + 16 + tx;
    #pragma unroll 8
    for (int kk = 0; kk < 64; ++kk) {
        float4 a  = a4[kk * 16];
        float4 wp = p4[kk * 32];
        float4 wq = q4[kk * 32];
        aP[0][0] = fmaf(a.x, wp.x, aP[0][0]); aP[0][1] = fmaf(a.x, wp.y, aP[0][1]);
        aP[0][2] = fmaf(a.x, wp.z, aP[0][2]); aP[0][3] = fmaf(a.x, wp.w, aP[0][3]);
        aP[1][0] = fmaf(a.y, wp.x, aP[1][0]); aP[1][1] = fmaf(a.y, wp.y, aP[1][1]);
        aP[1][2] = fmaf(a.y, wp.z, aP[1][2]); aP[1][3] = fmaf(a.y, wp.w, aP[1][3]);
        aP[2][0] = fmaf(a.z, wp.x, aP[2][0]); aP[2][1] = fmaf(a.z, wp.y, aP[2][1]);
        aP[2][2] = fmaf(a.z, wp.z, aP[2][2]); aP[2][3] = fmaf(a.z, wp.w, aP[2][3]);
        aP[3][0] = fmaf(a.w, wp.x, aP[3][0]); aP[3][1] = fmaf(a.w, wp.y, aP[3][1]);
        aP[3][2] = fmaf(a.w, wp.z, aP[3][2]); aP[3][3] = fmaf(a.w, wp.w, aP[3][3]);
        aQ[0][0] = fmaf(a.x, wq.x, aQ[0][0]); aQ[0][1] = fmaf(a.x, wq.y, aQ[0][1]);
        aQ[0][2] = fmaf(a.x, wq.z, aQ[0][2]); aQ[0][3] = fmaf(a.x, wq.w, aQ[0][3]);
        aQ[1][0] = fmaf(a.y, wq.x, aQ[1][0]); aQ[1][1] = fmaf(a.y, wq.y, aQ[1][1]);
        aQ[1][2] = fmaf(a.y, wq.z, aQ[1][2]); aQ[1][3] = fmaf(a.y, wq.w, aQ[1][3]);
        aQ[2][0] = fmaf(a.z, wq.x, aQ[2][0]); aQ[2][1] = fmaf(a.z, wq.y, aQ[2][1]);
        aQ[2][2] = fmaf(a.z, wq.z, aQ[2][2]); aQ[2][3] = fmaf(a.z, wq.w, aQ[2][3]);
        aQ[3][0] = fmaf(a.w, wq.x, aQ[3][0]); aQ[3][1] = fmaf(a.w, wq.y, aQ[3][1]);
        aQ[3][2] = fmaf(a.w, wq.z, aQ[3][2]); aQ[3][3] = fmaf(a.w, wq.w, aQ[3][3]);
    }
    #pragma unroll
    for (int i = 0; i < 4; ++i) {
        size_t row = (size_t)(g0 + ty * 4 + i) * 64;
        float4 vp; vp.x = aP[i][0]; vp.y = aP[i][1]; vp.z = aP[i][2]; vp.w = aP[i][3];
        float4 vq; vq.x = aQ[i][0]; vq.y = aQ[i][1]; vq.z = aQ[i][2]; vq.w = aQ[i][3];
        ((float4*)(P + row))[tx] = vp;
        ((float4*)(Q + row))[tx] = vq;
    }
}

// ---------------- K4: gather + max/min over k + global sum/sumsq --------------
__global__ __launch_bounds__(256) void k_stats(const float* __restrict__ P,
                                               const float* __restrict__ Q,
                                               const int* __restrict__ idx,
                                               float* __restrict__ Mx,
                                               float* __restrict__ Mn,
                                               float* __restrict__ gsum,
                                               float* __restrict__ gsum2) {
    const int tid = threadIdx.x;
    const int o = tid & 63, ng = tid >> 6;
    const int b = blockIdx.y;
    const int n0 = blockIdx.x * 16;
    const float* Pb = P + (((size_t)b << 12) * 64);
    float ssum = 0.f, ssq = 0.f;
    for (int j = 0; j < 4; ++j) {
        int n = n0 + ng * 4 + j;
        size_t base = ((size_t)b << 12) + n;
        float qv = Q[base * 64 + o];
        const int* ip = idx + base * 16;
        float vmax = -3.4e38f, vmin = 3.4e38f;
        #pragma unroll
        for (int k = 0; k < 16; ++k) {
            int m = ip[k];
            float v = Pb[(size_t)m * 64 + o] + qv;
            vmax = fmaxf(vmax, v);
            vmin = fminf(vmin, v);
            ssum += v;
            ssq  = fmaf(v, v, ssq);
        }
        Mx[base * 64 + o] = vmax;
        Mn[base * 64 + o] = vmin;
    }
    __shared__ float red[8][64];
    red[ng][o] = ssum;
    red[ng + 4][o] = ssq;
    __syncthreads();
    if (tid < 64) {
        float s  = red[0][o] + red[1][o] + red[2][o] + red[3][o];
        float s2 = red[4][o] + red[5][o] + red[6][o] + red[7][o];
        atomicAdd(&gsum[o], s);
        atomicAdd(&gsum2[o], s2);
    }
}

// ---------------- K5: BN + LeakyReLU + transpose to [b][o][n] -----------------
__global__ __launch_bounds__(256) void k_final(const float* __restrict__ Mx,
                                               const float* __restrict__ Mn,
                                               const float* __restrict__ gsum,
                                               const float* __restrict__ gsum2,
                                               const float* __restrict__ gamma,
                                               const float* __restrict__ beta,
                                               float* __restrict__ out) {
    __shared__ float tX[64 * 65], tN[64 * 65];
    const int tid = threadIdx.x;
    const int b = blockIdx.y;
    const int n0 = blockIdx.x * 64;
    size_t base = ((size_t)b << 12) + n0;
    for (int i = tid; i < 4096; i += 256) {
        int nl = i >> 6, o = i & 63;
        tX[nl * 65 + o] = Mx[(base + nl) * 64 + o];
        tN[nl * 65 + o] = Mn[(base + nl) * 64 + o];
    }
    __syncthreads();
    const int lane = tid & 63, wv = tid >> 6;
    const float inv = 1.0f / 524288.0f;
    for (int oo = 0; oo < 16; ++oo) {
        int o = wv * 16 + oo;
        float mean = gsum[o] * inv;
        float var  = gsum2[o] * inv - mean * mean;
        float scv  = gamma[o] * rsqrtf(var + 1e-5f);
        float bsv  = beta[o] - mean * scv;
        float M = (scv >= 0.f) ? tX[lane * 65 + o] : tN[lane * 65 + o];
        float v = fmaf(scv, M, bsv);
        out[((size_t)b * 64 + o) * 4096 + n0 + lane] = (v >= 0.f) ? v : 0.2f * v;
    }
}

extern "C" void kernel_launch(void* const* d_in, const int* in_sizes, int n_in,
                              void* d_out, int out_size, void* d_ws, size_t ws_size,
                              hipStream_t stream) {
    const float* x     = (const float*)d_in[0];
    const float* W     = (const float*)d_in[1];
    const float* gamma = (const float*)d_in[2];
    const float* beta  = (const float*)d_in[3];
    float* out = (float*)d_out;

    char* ws = (char*)d_ws;
    double* xx   = (double*)(ws);                      // 256 KB
    float* gsum  = (float*)(ws + 262144);              // 256 B
    float* gsum2 = (float*)(ws + 262400);              // 256 B
    int*   idx   = (int*)  (ws + 393216);              // 2 MB
    float* P     = (float*)(ws + 2490368);             // 8 MB
    float* Q     = (float*)(ws + 10878976);            // 8 MB
    float* Mx    = (float*)(ws + 19267584);            // 8 MB
    float* Mn    = (float*)(ws + 27656192);            // 8 MB (end ~34.4 MB)

    hipMemsetAsync(gsum, 0, 512, stream);
    k_xx   <<<dim3(128),      256, 0, stream>>>(x, xx);
    k_knn  <<<dim3(64, 8),    256, 0, stream>>>(x, xx, idx);
    k_pq   <<<dim3(512),      256, 0, stream>>>(x, W, P, Q);
    k_stats<<<dim3(256, 8),   256, 0, stream>>>(P, Q, idx, Mx, Mn, gsum, gsum2);
    k_final<<<dim3(64, 8),    256, 0, stream>>>(Mx, Mn, gsum, gsum2, gamma, beta, out);
}

// Round 6
// 469.158 us; speedup vs baseline: 2.5186x; 2.5186x over previous
//
#include <hip/hip_runtime.h>

#define NPTS 4096
#define NCH  64
#define NB   8
#define KNN  16

typedef _Float16 h8 __attribute__((ext_vector_type(8)));
typedef float    f4 __attribute__((ext_vector_type(4)));
typedef unsigned long long ull;

// ---------------- K1: xx (f64) + transposed f16 hi/lo split ------------------
// xhT/xlT: [b][n][c] half. x = hi + lo captures ~22 mantissa bits (np-level).
__global__ __launch_bounds__(256) void k_prep(const float* __restrict__ x,
                                              double* __restrict__ xx,
                                              _Float16* __restrict__ xhT,
                                              _Float16* __restrict__ xlT) {
    __shared__ float tile[64 * 65];
    const int tid = threadIdx.x;
    const int blk = blockIdx.x;
    const int b = blk >> 6, n0 = (blk & 63) << 6;
    const float* xb = x + (size_t)b * NCH * NPTS;
    for (int i = tid; i < 4096; i += 256) {
        int c = i >> 6, nn = i & 63;
        tile[c * 65 + nn] = xb[(size_t)c * NPTS + n0 + nn];
    }
    __syncthreads();
    if (tid < 64) {
        double a = 0.0;
        #pragma unroll
        for (int c = 0; c < 64; ++c) {
            double v = (double)tile[c * 65 + tid];
            a = fma(v, v, a);
        }
        xx[((size_t)b << 12) + n0 + tid] = a;
    }
    for (int i = tid; i < 4096; i += 256) {
        int n = i >> 6, c = i & 63;
        float v = tile[c * 65 + n];
        _Float16 h = (_Float16)v;
        _Float16 l = (_Float16)(v - (float)h);
        size_t o = (((size_t)b << 12) + n0 + n) * 64 + c;
        xhT[o] = h;
        xlT[o] = l;
    }
}

// ---------------- K2: KNN top-16, f16-split MFMA, in-register scan ------------
// D = M·Q per tile: lane (g,j) reg r = dot(m_{m0+16mt+4g+r}, q_{q0+16w+j}) ->
// lane scans its OWN query's candidates right out of the accumulator.
// Probe verifies layout vs f64 ground truth; fallback = exact f64 VALU GEMM.
__global__ __launch_bounds__(256) void k_knn(const float* __restrict__ x,
                                             const double* __restrict__ xx,
                                             const _Float16* __restrict__ xhT,
                                             const _Float16* __restrict__ xlT,
                                             int* __restrict__ idx_out) {
    __shared__ __align__(16) char ldsbuf[34816];   // union: fallback tiles / merge
    __shared__ int okflag;
    const int tid = threadIdx.x, lane = tid & 63, w = tid >> 6;
    const int g = lane >> 4, j = lane & 15;
    const int b = blockIdx.y, q0 = blockIdx.x * 64;
    const size_t bbase = (size_t)b << 12;
    const _Float16* Hb = xhT + bbase * 64;
    const _Float16* Lb = xlT + bbase * 64;
    const double*  xxb = xx + bbase;

    // B-frags: col j = this lane's query, k = kk2*32 + 8g + e
    const int qcol = q0 + 16 * w + j;
    h8 Bh[2], Bl[2];
    #pragma unroll
    for (int kk = 0; kk < 2; ++kk) {
        size_t o = (size_t)qcol * 64 + kk * 32 + 8 * g;
        Bh[kk] = *(const h8*)(Hb + o);
        Bl[kk] = *(const h8*)(Lb + o);
    }

    if (tid == 0) okflag = 1;
    __syncthreads();

    // ---- asymmetric layout probe: A rows = queries shifted by 1 ----
    {
        const int rsh = q0 + 16 * w + ((j + 1) & 15);
        f4 acc = {0.f, 0.f, 0.f, 0.f};
        #pragma unroll
        for (int kk = 0; kk < 2; ++kk) {
            size_t o = (size_t)rsh * 64 + kk * 32 + 8 * g;
            h8 Ah = *(const h8*)(Hb + o);
            h8 Al = *(const h8*)(Lb + o);
            acc = __builtin_amdgcn_mfma_f32_16x16x32_f16(Ah, Bh[kk], acc, 0, 0, 0);
            acc = __builtin_amdgcn_mfma_f32_16x16x32_f16(Ah, Bl[kk], acc, 0, 0, 0);
            acc = __builtin_amdgcn_mfma_f32_16x16x32_f16(Al, Bh[kk], acc, 0, 0, 0);
        }
        bool bad = false;
        #pragma unroll
        for (int rr = 0; rr < 2; ++rr) {
            const int r = rr ? 3 : 0;
            const int urow = q0 + 16 * w + ((4 * g + r + 1) & 15);
            double tgt = 0.0;
            #pragma unroll 4
            for (int c = 0; c < 64; ++c) {
                double av = (double)(float)Hb[(size_t)urow * 64 + c]
                          + (double)(float)Lb[(size_t)urow * 64 + c];
                double bv = (double)(float)Hb[(size_t)qcol * 64 + c]
                          + (double)(float)Lb[(size_t)qcol * 64 + c];
                tgt = fma(av, bv, tgt);
            }
            double got = (double)acc[r];
            if (fabs(got - tgt) > 1e-3 * (1.0 + fabs(tgt))) bad = true;
        }
        if (__any(bad ? 1 : 0)) okflag = 0;   // benign same-value race
    }
    __syncthreads();
    const bool mfma_ok = (okflag != 0);

    double s[16];
    #pragma unroll
    for (int i = 0; i < 16; ++i) s[i] = 0.0;

    if (mfma_ok) {
        for (int t = 0; t < 64; ++t) {
            const int m0 = t * 64;
            #pragma unroll
            for (int mt = 0; mt < 4; ++mt) {
                const int arow = m0 + 16 * mt + j;
                f4 acc = {0.f, 0.f, 0.f, 0.f};
                #pragma unroll
                for (int kk = 0; kk < 2; ++kk) {
                    size_t o = (size_t)arow * 64 + kk * 32 + 8 * g;
                    h8 Ah = *(const h8*)(Hb + o);
                    h8 Al = *(const h8*)(Lb + o);
                    acc = __builtin_amdgcn_mfma_f32_16x16x32_f16(Ah, Bh[kk], acc, 0, 0, 0);
                    acc = __builtin_amdgcn_mfma_f32_16x16x32_f16(Ah, Bl[kk], acc, 0, 0, 0);
                    acc = __builtin_amdgcn_mfma_f32_16x16x32_f16(Al, Bh[kk], acc, 0, 0, 0);
                }
                const int mbase = m0 + 16 * mt + 4 * g;
                #pragma unroll
                for (int r = 0; r < 4; ++r) {
                    const int m = mbase + r;
                    double dv = fma(2.0, (double)acc[r], -xxb[m]);
                    double pv = dv + 4096.0;
                    ull bits = (((ull)__double_as_longlong(pv)) & 0xFFFFFFFFFFFFF000ULL)
                             | (ull)(4095 - m);
                    double v = __longlong_as_double((long long)bits);
                    #pragma unroll
                    for (int i = 0; i < 15; ++i) s[i] = fmin(s[i + 1], fmax(v, s[i]));
                    s[15] = fmax(v, s[15]);
                }
            }
        }
    } else {
        // fallback: exact f64 VALU dots from original x, LDS-staged (round-2 semantics)
        float* fbQ = (float*)ldsbuf;
        float* fbM = ((float*)ldsbuf) + 64 * 66;
        const float* xb = x + (size_t)b * NCH * NPTS;
        for (int i = tid; i < 4096; i += 256) {
            int c = i >> 6, q = i & 63;
            fbQ[q * 66 + c] = xb[(size_t)c * NPTS + q0 + q];
        }
        for (int t = 0; t < 64; ++t) {
            const int m0 = t * 64;
            __syncthreads();
            for (int i = tid; i < 4096; i += 256) {
                int c = i >> 6, m = i & 63;
                fbM[m * 66 + c] = xb[(size_t)c * NPTS + m0 + m];
            }
            __syncthreads();
            const float* qp = fbQ + (16 * w + j) * 66;
            #pragma unroll
            for (int mt = 0; mt < 4; ++mt) {
                #pragma unroll
                for (int r = 0; r < 4; ++r) {
                    const int ml = 16 * mt + 4 * g + r, m = m0 + ml;
                    const float* mp = fbM + ml * 66;
                    double dot = 0.0;
                    #pragma unroll 8
                    for (int c = 0; c < 64; ++c)
                        dot = fma((double)qp[c], (double)mp[c], dot);
                    double dv = fma(2.0, dot, -xxb[m]);
                    double pv = dv + 4096.0;
                    ull bits = (((ull)__double_as_longlong(pv)) & 0xFFFFFFFFFFFFF000ULL)
                             | (ull)(4095 - m);
                    double v = __longlong_as_double((long long)bits);
                    #pragma unroll
                    for (int i = 0; i < 15; ++i) s[i] = fmin(s[i + 1], fmax(v, s[i]));
                    s[15] = fmax(v, s[15]);
                }
            }
        }
    }

    // merge 4 scanner lanes per query (pad stride 17 doubles: conflict-free)
    double* mg = (double*)ldsbuf;
    __syncthreads();
    #pragma unroll
    for (int i = 0; i < 16; ++i) mg[(size_t)tid * 17 + i] = s[i];
    __syncthreads();
    if (tid < 64) {
        double tb[16];
        #pragma unroll
        for (int i = 0; i < 16; ++i) tb[i] = 0.0;
        #pragma unroll
        for (int g2 = 0; g2 < 4; ++g2) {
            const double* src = mg + (size_t)(64 * (tid >> 4) + 16 * g2 + (tid & 15)) * 17;
            #pragma unroll
            for (int e = 0; e < 16; ++e) {
                double v = src[e];
                #pragma unroll
                for (int i = 0; i < 15; ++i) tb[i] = fmin(tb[i + 1], fmax(v, tb[i]));
                tb[15] = fmax(v, tb[15]);
            }
        }
        int* op = idx_out + (bbase + q0 + tid) * KNN;
        #pragma unroll
        for (int i = 0; i < 16; ++i) {
            int code = (int)((ull)__double_as_longlong(tb[i]) & 0xFFFULL);
            op[i] = 4095 - code;   // order within k never matters downstream
        }
    }
}

// ---------------- K3: P = W1 * x ; Q = (W2 - W1) * x  (both [b][n][o]) --------
__global__ __launch_bounds__(256) void k_pq(const float* __restrict__ x,
                                            const float* __restrict__ W,
                                            float* __restrict__ P,
                                            float* __restrict__ Q) {
    __shared__ __align__(16) float sX[4096];
    __shared__ __align__(16) float sWt[8192];
    const int tid = threadIdx.x;
    const int g0  = blockIdx.x * 64;
    const int b   = g0 >> 12;
    const int n0  = g0 & 4095;
    const float* xb = x + (size_t)b * NCH * NPTS;

    for (int i = tid; i < 8192; i += 256) {
        int c = i >> 7, oc = i & 127;
        float wv;
        if (oc < 64) wv = W[oc * 128 + c];
        else { int o = oc - 64; wv = W[o * 128 + 64 + c] - W[o * 128 + c]; }
        sWt[c * 128 + oc] = wv;
    }
    for (int i = tid; i < 4096; i += 256) {
        int c = i >> 6, m = i & 63;
        sX[i] = xb[(size_t)c * NPTS + n0 + m];
    }
    __syncthreads();

    const int ty = tid >> 4, tx = tid & 15;
    float aP[4][4], aQ[4][4];
    #pragma unroll
    for (int i = 0; i < 4; ++i)
        #pragma unroll
        for (int jj = 0; jj < 4; ++jj) { aP[i][jj] = 0.f; aQ[i][jj] = 0.f; }

    const float4* a4 = (const float4*)sX + ty;
    const float4* p4 = (const float4*)sWt + tx;
    const float4* q4 = (const float4*)sWt + 16 + tx;
    #pragma unroll 8
    for (int kk = 0; kk < 64; ++kk) {
        float4 a  = a4[kk * 16];
        float4 wp = p4[kk * 32];
        float4 wq = q4[kk * 32];
        aP[0][0] = fmaf(a.x, wp.x, aP[0][0]); aP[0][1] = fmaf(a.x, wp.y, aP[0][1]);
        aP[0][2] = fmaf(a.x, wp.z, aP[0][2]); aP[0][3] = fmaf(a.x, wp.w, aP[0][3]);
        aP[1][0] = fmaf(a.y, wp.x, aP[1][0]); aP[1][1] = fmaf(a.y, wp.y, aP[1][1]);
        aP[1][2] = fmaf(a.y, wp.z, aP[1][2]); aP[1][3] = fmaf(a.y, wp.w, aP[1][3]);
        aP[2][0] = fmaf(a.z, wp.x, aP[2][0]); aP[2][1] = fmaf(a.z, wp.y, aP[2][1]);
        aP[2][2] = fmaf(a.z, wp.z, aP[2][2]); aP[2][3] = fmaf(a.z, wp.w, aP[2][3]);
        aP[3][0] = fmaf(a.w, wp.x, aP[3][0]); aP[3][1] = fmaf(a.w, wp.y, aP[3][1]);
        aP[3][2] = fmaf(a.w, wp.z, aP[3][2]); aP[3][3] = fmaf(a.w, wp.w, aP[3][3]);
        aQ[0][0] = fmaf(a.x, wq.x, aQ[0][0]); aQ[0][1] = fmaf(a.x, wq.y, aQ[0][1]);
        aQ[0][2] = fmaf(a.x, wq.z, aQ[0][2]); aQ[0][3] = fmaf(a.x, wq.w, aQ[0][3]);
        aQ[1][0] = fmaf(a.y, wq.x, aQ[1][0]); aQ[1][1] = fmaf(a.y, wq.y, aQ[1][1]);
        aQ[1][2] = fmaf(a.y, wq.z, aQ[1][2]); aQ[1][3] = fmaf(a.y, wq.w, aQ[1][3]);
        aQ[2][0] = fmaf(a.z, wq.x, aQ[2][0]); aQ[2][1] = fmaf(a.z, wq.y, aQ[2][1]);
        aQ[2][2] = fmaf(a.z, wq.z, aQ[2][2]); aQ[2][3] = fmaf(a.z, wq.w, aQ[2][3]);
        aQ[3][0] = fmaf(a.w, wq.x, aQ[3][0]); aQ[3][1] = fmaf(a.w, wq.y, aQ[3][1]);
        aQ[3][2] = fmaf(a.w, wq.z, aQ[3][2]); aQ[3][3] = fmaf(a.w, wq.w, aQ[3][3]);
    }
    #pragma unroll
    for (int i = 0; i < 4; ++i) {
        size_t row = (size_t)(g0 + ty * 4 + i) * 64;
        float4 vp; vp.x = aP[i][0]; vp.y = aP[i][1]; vp.z = aP[i][2]; vp.w = aP[i][3];
        float4 vq; vq.x = aQ[i][0]; vq.y = aQ[i][1]; vq.z = aQ[i][2]; vq.w = aQ[i][3];
        ((float4*)(P + row))[tx] = vp;
        ((float4*)(Q + row))[tx] = vq;
    }
}

// ---------------- K4: gather + max/min over k + global sum/sumsq --------------
__global__ __launch_bounds__(256) void k_stats(const float* __restrict__ P,
                                               const float* __restrict__ Q,
                                               const int* __restrict__ idx,
                                               float* __restrict__ Mx,
                                               float* __restrict__ Mn,
                                               float* __restrict__ gsum,
                                               float* __restrict__ gsum2) {
    const int tid = threadIdx.x;
    const int o = tid & 63, ng = tid >> 6;
    const int b = blockIdx.y;
    const int n0 = blockIdx.x * 16;
    const float* Pb = P + (((size_t)b << 12) * 64);
    float ssum = 0.f, ssq = 0.f;
    for (int jj = 0; jj < 4; ++jj) {
        int n = n0 + ng * 4 + jj;
        size_t base = ((size_t)b << 12) + n;
        float qv = Q[base * 64 + o];
        const int* ip = idx + base * 16;
        float vmax = -3.4e38f, vmin = 3.4e38f;
        #pragma unroll
        for (int k = 0; k < 16; ++k) {
            int m = ip[k];
            float v = Pb[(size_t)m * 64 + o] + qv;
            vmax = fmaxf(vmax, v);
            vmin = fminf(vmin, v);
            ssum += v;
            ssq  = fmaf(v, v, ssq);
        }
        Mx[base * 64 + o] = vmax;
        Mn[base * 64 + o] = vmin;
    }
    __shared__ float red[8][64];
    red[ng][o] = ssum;
    red[ng + 4][o] = ssq;
    __syncthreads();
    if (tid < 64) {
        float ss  = red[0][o] + red[1][o] + red[2][o] + red[3][o];
        float ss2 = red[4][o] + red[5][o] + red[6][o] + red[7][o];
        atomicAdd(&gsum[o], ss);
        atomicAdd(&gsum2[o], ss2);
    }
}

// ---------------- K5: BN + LeakyReLU + transpose to [b][o][n] -----------------
__global__ __launch_bounds__(256) void k_final(const float* __restrict__ Mx,
                                               const float* __restrict__ Mn,
                                               const float* __restrict__ gsum,
                                               const float* __restrict__ gsum2,
                                               const float* __restrict__ gamma,
                                               const float* __restrict__ beta,
                                               float* __restrict__ out) {
    __shared__ float tX[64 * 65], tN[64 * 65];
    const int tid = threadIdx.x;
    const int b = blockIdx.y;
    const int n0 = blockIdx.x * 64;
    size_t base = ((size_t)b << 12) + n0;
    for (int i = tid; i < 4096; i += 256) {
        int nl = i >> 6, o = i & 63;
        tX[nl * 65 + o] = Mx[(base + nl) * 64 + o];
        tN[nl * 65 + o] = Mn[(base + nl) * 64 + o];
    }
    __syncthreads();
    const int lane = tid & 63, wv = tid >> 6;
    const float inv = 1.0f / 524288.0f;
    for (int oo = 0; oo < 16; ++oo) {
        int o = wv * 16 + oo;
        float mean = gsum[o] * inv;
        float var  = gsum2[o] * inv - mean * mean;
        float scv  = gamma[o] * rsqrtf(var + 1e-5f);
        float bsv  = beta[o] - mean * scv;
        float M = (scv >= 0.f) ? tX[lane * 65 + o] : tN[lane * 65 + o];
        float v = fmaf(scv, M, bsv);
        out[((size_t)b * 64 + o) * 4096 + n0 + lane] = (v >= 0.f) ? v : 0.2f * v;
    }
}

extern "C" void kernel_launch(void* const* d_in, const int* in_sizes, int n_in,
                              void* d_out, int out_size, void* d_ws, size_t ws_size,
                              hipStream_t stream) {
    const float* x     = (const float*)d_in[0];
    const float* W     = (const float*)d_in[1];
    const float* gamma = (const float*)d_in[2];
    const float* beta  = (const float*)d_in[3];
    float* out = (float*)d_out;

    char* ws = (char*)d_ws;
    double*    xx    = (double*)(ws);                    // 256 KB
    float*     gsum  = (float*)(ws + 262144);            // 256 B
    float*     gsum2 = (float*)(ws + 262400);            // 256 B
    int*       idx   = (int*)  (ws + 393216);            // 2 MB
    _Float16*  xhT   = (_Float16*)(ws + 2490368);        // 4 MB
    _Float16*  xlT   = (_Float16*)(ws + 6684672);        // 4 MB
    float*     P     = (float*)(ws + 10878976);          // 8 MB
    float*     Q     = (float*)(ws + 19267584);          // 8 MB
    float*     Mx    = (float*)(ws + 2490368);           // 8 MB (reuses xhT+xlT, dead after k_knn)
    float*     Mn    = (float*)(ws + 27656192);          // 8 MB (end ~36 MB, proven size)

    hipMemsetAsync(gsum, 0, 512, stream);
    k_prep <<<dim3(512),      256, 0, stream>>>(x, xx, xhT, xlT);
    k_knn  <<<dim3(64, 8),    256, 0, stream>>>(x, xx, xhT, xlT, idx);
    k_pq   <<<dim3(512),      256, 0, stream>>>(x, W, P, Q);
    k_stats<<<dim3(256, 8),   256, 0, stream>>>(P, Q, idx, Mx, Mn, gsum, gsum2);
    k_final<<<dim3(64, 8),    256, 0, stream>>>(Mx, Mn, gsum, gsum2, gamma, beta, out);
}